// Round 10
// baseline (487.240 us; speedup 1.0000x reference)
//
#include <hip/hip_runtime.h>

#define S 128
#define N 32
#define D 300
#define DP 320
#define E 64
#define R 4
#define V 50000
#define VP 50048
#define ND 9600
#define KY 1504   // stacked K for P0 GEMM: 4*300 conv + 300 W0 + 4 pad
#define DPAD 304  // padded N rows for Bt matrices

typedef unsigned short ushortT;
typedef __attribute__((ext_vector_type(8))) short short8;
typedef __attribute__((ext_vector_type(4))) short short4v;
typedef __attribute__((ext_vector_type(4))) float floatx4;
typedef __attribute__((ext_vector_type(8))) _Float16 half8;

__device__ inline float bf2f(ushortT h) {
    unsigned u = ((unsigned)h) << 16;
    float f;
    __builtin_memcpy(&f, &u, 4);
    return f;
}

__device__ inline float bfbits_lo(unsigned u) {
    unsigned b = u << 16;
    float f;
    __builtin_memcpy(&f, &b, 4);
    return f;
}

__device__ inline float bfbits_hi(unsigned u) {
    unsigned b = u & 0xffff0000u;
    float f;
    __builtin_memcpy(&f, &b, 4);
    return f;
}

__device__ inline ushortT f2bf(float f) {
    unsigned u;
    __builtin_memcpy(&u, &f, 4);
    unsigned r = (u + 0x7fffu + ((u >> 16) & 1u)) >> 16;
    return (ushortT)r;
}

__device__ inline float ldf(const void* p, size_t i, int isb) {
    return isb ? bf2f(((const ushortT*)p)[i]) : ((const float*)p)[i];
}

// ---------------- K_detect: decide input dtype ------------------------------
__global__ void k_detect(const void* X, int* flag) {
    __shared__ int bad;
    if (threadIdx.x == 0) bad = 0;
    __syncthreads();
    const ushortT* p = (const ushortT*)X;
    int b = 0;
    for (int i = threadIdx.x; i < 4096; i += 256) {
        float v = bf2f(p[i]);
        if (!(v > -2.f && v < 2.f)) b = 1;  // catches NaN/Inf too
    }
    if (b) atomicOr(&bad, 1);
    __syncthreads();
    if (threadIdx.x == 0) flag[0] = bad ? 0 : 1;
}

// ---------------- K_prep: fused weight transposes (twg | tws) ---------------
__global__ void k_prep(const int* __restrict__ flag, const void* __restrict__ Wg,
                       const void* __restrict__ convW, const void* __restrict__ W0,
                       ushortT* __restrict__ wgt, ushortT* __restrict__ wst) {
    int isb = flag[0];
    __shared__ float tile[32][33];
    int bx = blockIdx.x;
    int d0 = blockIdx.y * 32;
    int tx = threadIdx.x & 31, ty = threadIdx.x >> 5;  // 32x8
    if (bx < ND / 32) {  // twg role
        int k0 = bx * 32;
        for (int i = ty; i < 32; i += 8) {
            int d = d0 + tx;
            tile[i][tx] = (d < D) ? ldf(Wg, (size_t)(k0 + i) * D + d, isb) : 0.f;
        }
        __syncthreads();
        for (int i = ty; i < 32; i += 8) {
            int d = d0 + i;
            if (d < DPAD) wgt[(size_t)d * ND + k0 + tx] = f2bf(tile[tx][i]);
        }
    } else {  // tws role
        int k0 = (bx - ND / 32) * 32;
        for (int i = ty; i < 32; i += 8) {
            int kp = k0 + i, d = d0 + tx;
            float v = 0.f;
            if (d < D && kp < 1500)
                v = (kp < 1200) ? ldf(convW, (size_t)kp * D + d, isb)
                                : ldf(W0, (size_t)(kp - 1200) * D + d, isb);
            tile[i][tx] = v;
        }
        __syncthreads();
        for (int i = ty; i < 32; i += 8) {
            int d = d0 + i;
            if (d < DPAD) wst[(size_t)d * KY + k0 + tx] = f2bf(tile[tx][i]);
        }
    }
}

// ---------------- K_gyb: fused gather (block's 32 rows) + yb build ----------
__global__ void k_gyb(const int* __restrict__ flag, const int* __restrict__ xi,
                      const void* __restrict__ X, const int* __restrict__ ei,
                      const int* __restrict__ et, ushortT* __restrict__ gxb,
                      ushortT* __restrict__ yb) {
    int isb = flag[0];
    int s = blockIdx.x;
    int t = threadIdx.x;  // 320
    __shared__ ushortT gl[N][D];  // 19.2 KB
    __shared__ int se[E], de[E], te[E];
    __shared__ float disv[R][N];
    if (t < E) {
        se[t] = ei[(size_t)s * 2 * E + t];
        de[t] = ei[(size_t)s * 2 * E + E + t];
        te[t] = et[(size_t)s * E + t];
    }
    if (t < D) {
#pragma unroll 4
        for (int r = 0; r < N; ++r) {
            int node = xi[s * N + r];
            ushortT v = isb ? ((const ushortT*)X)[(size_t)node * D + t]
                            : f2bf(((const float*)X)[(size_t)node * D + t]);
            gl[r][t] = v;
            gxb[(size_t)(s * N + r) * D + t] = v;
        }
    }
    __syncthreads();
    if (t < R * N) {
        int r = t >> 5, n = t & 31;
        float c = 1.f;
        for (int e = 0; e < E; ++e) c += (te[e] == r && de[e] == n) ? 1.f : 0.f;
        disv[r][n] = rsqrtf(c);
    }
    __syncthreads();
    if (t < D) {
        float g0 = bf2f(gl[0][t]);
        float yy[R];
#pragma unroll
        for (int r = 0; r < R; ++r) yy[r] = g0 * disv[r][0] * disv[r][0];
        for (int e = 0; e < E; ++e) {
            if (de[e] == 0) {
                int r = te[e];
                yy[r] += disv[r][se[e]] * disv[r][0] * bf2f(gl[se[e]][t]);
            }
        }
#pragma unroll
        for (int r = 0; r < R; ++r) yb[(size_t)s * KY + r * D + t] = f2bf(yy[r]);
        yb[(size_t)s * KY + 4 * D + t] = gl[0][t];  // gx0 slot for W0
    }
    if (t < 4) yb[(size_t)s * KY + 1500 + t] = 0;
}

// ---------------- K_gemm2: both GEMMs in one launch (z-encoded) -------------
__global__ __launch_bounds__(256) void k_gemm2(const ushortT* __restrict__ gxb,
                                               const ushortT* __restrict__ wgt,
                                               const ushortT* __restrict__ yb,
                                               const ushortT* __restrict__ wst,
                                               float* __restrict__ apart,
                                               float* __restrict__ ppart, int nza, int nzp) {
    int wave = threadIdx.x >> 6, lane = threadIdx.x & 63;
    int col = lane & 15, quad = lane >> 4;
    int m0 = blockIdx.x * 16, n0 = blockIdx.y * 16;
    int z = blockIdx.z;
    const ushortT *A, *Bt;
    float* C;
    int ld, kchunks, per, zz;
    if (z < nza) {
        A = gxb; Bt = wgt; C = apart; ld = ND; kchunks = ND / 32;
        zz = z; per = (kchunks + nza - 1) / nza;
    } else {
        A = yb; Bt = wst; C = ppart; ld = KY; kchunks = KY / 32;
        zz = z - nza; per = (kchunks + nzp - 1) / nzp;
    }
    int kbeg = zz * per;
    int kend = kbeg + per;
    if (kend > kchunks) kend = kchunks;
    floatx4 acc = {0.f, 0.f, 0.f, 0.f};
    const ushortT* ap = A + (size_t)(m0 + col) * ld + quad * 8;
    const ushortT* bp = Bt + (size_t)(n0 + col) * ld + quad * 8;
    for (int kc = kbeg + wave; kc < kend; kc += 4) {
        short8 a = *(const short8*)(ap + kc * 32);
        short8 b = *(const short8*)(bp + kc * 32);
        acc = __builtin_amdgcn_mfma_f32_16x16x32_bf16(a, b, acc, 0, 0, 0);
    }
    __shared__ float red[4][64][4];
#pragma unroll
    for (int i = 0; i < 4; ++i) red[wave][lane][i] = acc[i];
    __syncthreads();
    if (wave == 0) {
#pragma unroll
        for (int i = 0; i < 4; ++i) {
            float v = red[0][lane][i] + red[1][lane][i] + red[2][lane][i] + red[3][lane][i];
            int m = m0 + quad * 4 + i;
            int n = n0 + col;
            if (n < D) C[(size_t)zz * S * D + (size_t)m * D + n] = v;
        }
    }
}

// ---------------- K_red2: bulk z-reduce for BOTH partial arrays -------------
__global__ void k_red2(const float* __restrict__ apart, const float* __restrict__ ppart,
                       float* __restrict__ a, float* __restrict__ P0, int nza, int nzp) {
    int i = blockIdx.x * 256 + threadIdx.x;
    if (i < S * D) {
        float v = 0.f;
        for (int z = 0; z < nza; ++z) v += apart[(size_t)z * S * D + i];
        a[i] = v;
        float w = 0.f;
        for (int z = 0; z < nzp; ++z) w += ppart[(size_t)z * S * D + i];
        P0[i] = w;
    }
}

// ---------------- K6 v10: scan matvec on the MATRIX pipe --------------------
// Round-9 post-mortem: v9 == v7 (123us) -> scan is VALU-issue-bound (~245
// instr/wave/step, VALUBusy 64% on-CU) while MfmaUtil = 0.  v10 moves the
// m@Ug matvec to mfma_f32_16x16x32_f16 (M=1, A rows 1-15 zero):
//   - 19 N-tiles x 10 K-chunks = 190 mfma/step.  Wave w owns tile w with Ug
//     frags in REGISTERS (40 VGPR f16) and, for w<7, tile 12+w with frags in
//     LDS (70 KB).  Each wave accumulates over all K in-wave -> the cross-
//     wave partial reduce (part[] + 12-load tree) is GONE.
//   - fragment layouts pinned by this file's passing k_gemm: A lane holds
//     row=lane&15, k=(lane>>4)*8+i; B lane holds col=lane&15, k-consecutive;
//     C/D col=lane&15, row=(lane>>4)*4+reg -> y row 0 = lanes 0-15, reg 0.
//   - m lives in a double-buffered A-fragment IMAGE in LDS (2 x 10KB, zeroed
//     once): sigmoid lane (quad==0, col=j) writes f16 m[n] at slot
//     c*512+q*128+i (c=n>>5, q=(n>>3)&3, i=n&7); every wave builds A-frags
//     with 10 ds_read_b128 (lane*16B contiguous -> conflict-free).
//   - numerics = v9's (f16 x f16 -> f32 accum).
//   - one DS-only raw barrier/step (v9-proven form); a/P0 prefetch one step
//     ahead stays in flight across it.
__global__ __attribute__((amdgpu_flat_work_group_size(768, 768), amdgpu_waves_per_eu(2, 2))) void
k_scan(const int* __restrict__ flag, const float* __restrict__ a, const float* __restrict__ P0,
       const void* __restrict__ Ug, ushortT* __restrict__ x1p) {
    int isb = flag[0];
    int t = threadIdx.x;
    int w = t >> 6, lane = t & 63;  // w 0..11
    int quad = lane >> 4, col = lane & 15;
    bool has2 = w < 7;  // wave-uniform: second tile (12+w) via LDS frags
    __shared__ _Float16 ug_lds[7][10][512];  // 70 KB: tile 12+w, chunk c, lane*8+i
    __shared__ _Float16 aimg[2][10][512];    // 20 KB: double-buffered A-frag image
    // ---- preload Ug fragments (one-time) ----
    // reg tile w: lane holds Ug[c*32+quad*8+i][w*16+col], f16 (n<=191<300 ok)
    half8 ugr[10];
#pragma unroll
    for (int c = 0; c < 10; ++c) {
        half8 v;
#pragma unroll
        for (int i = 0; i < 8; ++i) {
            int k = c * 32 + quad * 8 + i;
            int n = w * 16 + col;
            v[i] = (_Float16)((k < D) ? ldf(Ug, (size_t)k * D + n, isb) : 0.f);
        }
        ugr[c] = v;
    }
    if (has2) {  // LDS tile 12+w: same layout, cols (12+w)*16+col (mask >=300)
#pragma unroll
        for (int c = 0; c < 10; ++c) {
#pragma unroll
            for (int i = 0; i < 8; ++i) {
                int k = c * 32 + quad * 8 + i;
                int n = (12 + w) * 16 + col;
                ug_lds[w][c][lane * 8 + i] =
                    (_Float16)((k < D && n < D) ? ldf(Ug, (size_t)k * D + n, isb) : 0.f);
            }
        }
    }
    // zero A-image (both buffers; slots k>=300 stay zero forever)
    for (int i = t; i < 2 * 10 * 512; i += 768) ((ushortT*)aimg)[i] = 0;
    // zero x1p pad columns [300,320) once
    for (int i = t; i < S * 20; i += 768) {
        int s = i / 20, d = 300 + (i % 20);
        x1p[(size_t)s * DP + d] = 0;
    }
    // epilogue ownership: lanes 0-15 (C row 0 = reg 0); n1 = w*16+col (reg
    // tile, always <192), n2 = (12+w)*16+col (LDS tile, mask <300).
    bool ep = quad == 0;
    int n1 = w * 16 + col;
    int n2 = (12 + w) * 16 + col;
    bool ep2 = ep && has2 && (n2 < D);
    // A-image halfword slot for m[n]: c=n>>5, q=(n>>3)&3, i=n&7
    int wi1 = (n1 >> 5) * 512 + ((n1 >> 3) & 3) * 128 + (n1 & 7);
    int wi2 = (n2 >> 5) * 512 + ((n2 >> 3) & 3) * 128 + (n2 & 7);
    float m1 = 0.f, m2 = 0.f;
    float av1 = 0.f, pv1 = 0.f, av2 = 0.f, pv2 = 0.f;
    if (ep) {
        av1 = a[n1];
        pv1 = P0[n1];
    }
    if (ep2) {
        av2 = a[n2];
        pv2 = P0[n2];
    }
    __syncthreads();  // init visibility (ug_lds, aimg zeros)
    int buf = 0;
    for (int s = 0; s < S; ++s) {
        // prefetch next step's a/P0 (stays in flight across the raw barrier)
        float an1 = 0.f, pn1 = 0.f, an2 = 0.f, pn2 = 0.f;
        if (ep && s + 1 < S) {
            an1 = a[(size_t)(s + 1) * D + n1];
            pn1 = P0[(size_t)(s + 1) * D + n1];
        }
        if (ep2 && s + 1 < S) {
            an2 = a[(size_t)(s + 1) * D + n2];
            pn2 = P0[(size_t)(s + 1) * D + n2];
        }
        floatx4 c1 = {0.f, 0.f, 0.f, 0.f};
        floatx4 c2 = {0.f, 0.f, 0.f, 0.f};
#pragma unroll
        for (int c = 0; c < 10; ++c) {
            half8 af = *(const half8*)&aimg[buf][c][lane * 8];
            c1 = __builtin_amdgcn_mfma_f32_16x16x32_f16(af, ugr[c], c1, 0, 0, 0);
            if (has2) {
                half8 bf = *(const half8*)&ug_lds[w][c][lane * 8];
                c2 = __builtin_amdgcn_mfma_f32_16x16x32_f16(af, bf, c2, 0, 0, 0);
            }
        }
        if (ep) {
            float pr = av1 + c1[0];
            float u = 1.f / (1.f + __expf(-pr));
            float nm = u * pv1 + (1.f - u) * m1;
            m1 = nm;
            ((_Float16*)aimg[buf ^ 1])[wi1] = (_Float16)nm;
            float x = nm > 0.f ? nm : 0.01f * nm;
            x1p[(size_t)s * DP + n1] = f2bf(x);
        }
        if (ep2) {
            float pr = av2 + c2[0];
            float u = 1.f / (1.f + __expf(-pr));
            float nm = u * pv2 + (1.f - u) * m2;
            m2 = nm;
            ((_Float16*)aimg[buf ^ 1])[wi2] = (_Float16)nm;
            float x = nm > 0.f ? nm : 0.01f * nm;
            x1p[(size_t)s * DP + n2] = f2bf(x);
        }
        // raw DS-only barrier (v9-proven): m writes drained, vmcnt in flight
        __builtin_amdgcn_sched_barrier(0);
        asm volatile("s_waitcnt lgkmcnt(0)" ::: "memory");
        __builtin_amdgcn_s_barrier();
        __builtin_amdgcn_sched_barrier(0);
        av1 = an1;
        pv1 = pn1;
        av2 = an2;
        pv2 = pn2;
        buf ^= 1;
    }
}

// ---------------- K7: logits = x1 @ lin_w^T + b via MFMA --------------------
__global__ __launch_bounds__(256) void k_logits(const int* __restrict__ flag,
                                                const ushortT* __restrict__ x1p,
                                                const void* __restrict__ lw,
                                                const void* __restrict__ lb,
                                                void* __restrict__ out) {
    int isb = flag[0];
    int wave = threadIdx.x >> 6, lane = threadIdx.x & 63;
    int col = lane & 15, quad = lane >> 4;
    int v = blockIdx.x * 64 + wave * 16 + col;
    int vv = v < V ? v : V - 1;
    floatx4 acc[8];
#pragma unroll
    for (int i = 0; i < 8; ++i) acc[i] = (floatx4){0.f, 0.f, 0.f, 0.f};
#pragma unroll
    for (int kc = 0; kc < 9; ++kc) {
        int k0 = kc * 32 + quad * 8;
        short8 b;
        if (isb) {
            const ushortT* bp = (const ushortT*)lw + (size_t)vv * D + k0;  // 8B aligned
            short4v lo = *(const short4v*)bp;
            short4v hi = *(const short4v*)(bp + 4);
            b = (short8){lo[0], lo[1], lo[2], lo[3], hi[0], hi[1], hi[2], hi[3]};
        } else {
            const float* bp = (const float*)lw + (size_t)vv * D + k0;  // 16B aligned
            floatx4 f0 = *(const floatx4*)bp;
            floatx4 f1 = *(const floatx4*)(bp + 4);
            b = (short8){(short)f2bf(f0[0]), (short)f2bf(f0[1]), (short)f2bf(f0[2]),
                         (short)f2bf(f0[3]), (short)f2bf(f1[0]), (short)f2bf(f1[1]),
                         (short)f2bf(f1[2]), (short)f2bf(f1[3])};
        }
#pragma unroll
        for (int st = 0; st < 8; ++st) {
            short8 aa = *(const short8*)(x1p + (size_t)(st * 16 + col) * DP + k0);
            acc[st] = __builtin_amdgcn_mfma_f32_16x16x32_bf16(aa, b, acc[st], 0, 0, 0);
        }
    }
    {  // tail chunk k=288..319 (lin_w valid only k<300; x1p zero-padded)
        int k0 = 288 + quad * 8;
        short8 b;
#pragma unroll
        for (int j = 0; j < 8; ++j) {
            int k = k0 + j;
            ushortT bv = 0;
            if (k < D)
                bv = isb ? ((const ushortT*)lw)[(size_t)vv * D + k]
                         : f2bf(((const float*)lw)[(size_t)vv * D + k]);
            b[j] = (short)bv;
        }
#pragma unroll
        for (int st = 0; st < 8; ++st) {
            short8 aa = *(const short8*)(x1p + (size_t)(st * 16 + col) * DP + k0);
            acc[st] = __builtin_amdgcn_mfma_f32_16x16x32_bf16(aa, b, acc[st], 0, 0, 0);
        }
    }
    if (v < V) {
        float bias = ldf(lb, v, isb);
#pragma unroll
        for (int st = 0; st < 8; ++st) {
#pragma unroll
            for (int i = 0; i < 4; ++i) {
                int s = st * 16 + quad * 4 + i;
                float val = acc[st][i] + bias;
                if (isb)
                    ((ushortT*)out)[(size_t)s * V + v] = f2bf(val);
                else
                    ((float*)out)[(size_t)s * V + v] = val;
            }
        }
    }
}

// ---------------- K8: fused logsumexp + in-place normalize + senses tail ----
__global__ __launch_bounds__(512) void k_norm(const int* __restrict__ flag,
                                              void* __restrict__ out) {
    int isb = flag[0];
    int s = blockIdx.x;
    int t = threadIdx.x;
    __shared__ float red[512];
    if (s == 0 && t < S) {
        if (isb)
            ((ushortT*)out)[(size_t)S * V + t] = 0;
        else
            ((float*)out)[(size_t)S * V + t] = 0.f;
    }
    float mx = -1e30f;
    if (isb) {
        const uint4* row = (const uint4*)((const ushortT*)out + (size_t)s * V);  // 6250 vecs
        for (int i = t; i < 6250; i += 512) {
            uint4 q = row[i];
            mx = fmaxf(mx, fmaxf(fmaxf(bfbits_lo(q.x), bfbits_hi(q.x)),
                                 fmaxf(bfbits_lo(q.y), bfbits_hi(q.y))));
            mx = fmaxf(mx, fmaxf(fmaxf(bfbits_lo(q.z), bfbits_hi(q.z)),
                                 fmaxf(bfbits_lo(q.w), bfbits_hi(q.w))));
        }
    } else {
        const floatx4* row = (const floatx4*)((const float*)out + (size_t)s * V);  // 12500 vecs
        for (int i = t; i < 12500; i += 512) {
            floatx4 q = row[i];
            mx = fmaxf(mx, fmaxf(fmaxf(q[0], q[1]), fmaxf(q[2], q[3])));
        }
    }
    red[t] = mx;
    __syncthreads();
    for (int o = 256; o > 0; o >>= 1) {
        if (t < o) red[t] = fmaxf(red[t], red[t + o]);
        __syncthreads();
    }
    float M = red[0];
    __syncthreads();
    float sm = 0.f;
    if (isb) {
        const uint4* row = (const uint4*)((const ushortT*)out + (size_t)s * V);
        for (int i = t; i < 6250; i += 512) {
            uint4 q = row[i];
            sm += __expf(bfbits_lo(q.x) - M) + __expf(bfbits_hi(q.x) - M) +
                  __expf(bfbits_lo(q.y) - M) + __expf(bfbits_hi(q.y) - M) +
                  __expf(bfbits_lo(q.z) - M) + __expf(bfbits_hi(q.z) - M) +
                  __expf(bfbits_lo(q.w) - M) + __expf(bfbits_hi(q.w) - M);
        }
    } else {
        const floatx4* row = (const floatx4*)((const float*)out + (size_t)s * V);
        for (int i = t; i < 12500; i += 512) {
            floatx4 q = row[i];
            sm += __expf(q[0] - M) + __expf(q[1] - M) + __expf(q[2] - M) + __expf(q[3] - M);
        }
    }
    red[t] = sm;
    __syncthreads();
    for (int o = 256; o > 0; o >>= 1) {
        if (t < o) red[t] += red[t + o];
        __syncthreads();
    }
    float lse = M + __logf(red[0]);
    if (isb) {
        uint4* row = (uint4*)((ushortT*)out + (size_t)s * V);
        for (int i = t; i < 6250; i += 512) {
            uint4 q = row[i];
            uint4 o;
            o.x = (unsigned)f2bf(bfbits_lo(q.x) - lse) |
                  ((unsigned)f2bf(bfbits_hi(q.x) - lse) << 16);
            o.y = (unsigned)f2bf(bfbits_lo(q.y) - lse) |
                  ((unsigned)f2bf(bfbits_hi(q.y) - lse) << 16);
            o.z = (unsigned)f2bf(bfbits_lo(q.z) - lse) |
                  ((unsigned)f2bf(bfbits_hi(q.z) - lse) << 16);
            o.w = (unsigned)f2bf(bfbits_lo(q.w) - lse) |
                  ((unsigned)f2bf(bfbits_hi(q.w) - lse) << 16);
            row[i] = o;
        }
    } else {
        floatx4* row = (floatx4*)((float*)out + (size_t)s * V);
        for (int i = t; i < 12500; i += 512) {
            floatx4 q = row[i];
            q[0] -= lse;
            q[1] -= lse;
            q[2] -= lse;
            q[3] -= lse;
            row[i] = q;
        }
    }
}

// ---------------- workspace layout (bytes, all 256-aligned) -----------------
#define OFF_FLAG 0
#define OFF_GXB 256
#define OFF_WGT 2457856
#define OFF_WST 8294656
#define OFF_YB 9209088
#define OFF_A 9594112
#define OFF_P0 9747712
#define OFF_X1P 9901312
#define OFF_STATS 9983232
#define OFF_PART 9983744  // optional z-split partial buffers (needs bigger ws)
#define PART_A_BYTES (4 * S * D * 4)
#define PART_P_BYTES (2 * S * D * 4)

extern "C" void kernel_launch(void* const* d_in, const int* in_sizes, int n_in, void* d_out,
                              int out_size, void* d_ws, size_t ws_size, hipStream_t stream) {
    const int* xi = (const int*)d_in[0];
    const int* ei = (const int*)d_in[1];
    const int* et = (const int*)d_in[2];
    const void* X = d_in[3];
    const void* convW = d_in[4];
    const void* W0 = d_in[5];
    const void* Wg = d_in[6];
    const void* Ug = d_in[7];
    const void* lw = d_in[8];
    const void* lb = d_in[9];
    char* ws = (char*)d_ws;

    int* flag = (int*)(ws + OFF_FLAG);
    ushortT* gxb = (ushortT*)(ws + OFF_GXB);
    ushortT* wgt = (ushortT*)(ws + OFF_WGT);
    ushortT* wst = (ushortT*)(ws + OFF_WST);
    ushortT* yb = (ushortT*)(ws + OFF_YB);
    float* a = (float*)(ws + OFF_A);
    float* P0 = (float*)(ws + OFF_P0);
    ushortT* x1p = (ushortT*)(ws + OFF_X1P);

    // z-split K only if workspace is big enough for partial buffers
    bool split = ws_size >= (size_t)(OFF_PART + PART_A_BYTES + PART_P_BYTES);
    int nza = split ? 4 : 1;
    int nzp = split ? 2 : 1;
    float* apart = split ? (float*)(ws + OFF_PART) : a;
    float* ppart = split ? (float*)(ws + OFF_PART + PART_A_BYTES) : P0;

    hipLaunchKernelGGL(k_detect, dim3(1), dim3(256), 0, stream, X, flag);
    hipLaunchKernelGGL(k_prep, dim3(ND / 32 + KY / 32, 10), dim3(256), 0, stream, flag, Wg,
                       convW, W0, wgt, wst);
    hipLaunchKernelGGL(k_gyb, dim3(S), dim3(DP), 0, stream, flag, xi, X, ei, et, gxb, yb);
    hipLaunchKernelGGL(k_gemm2, dim3(S / 16, 19, nza + nzp), dim3(256), 0, stream, gxb, wgt,
                       yb, wst, apart, ppart, nza, nzp);
    if (split)
        hipLaunchKernelGGL(k_red2, dim3((S * D + 255) / 256), dim3(256), 0, stream, apart,
                           ppart, a, P0, nza, nzp);
    hipLaunchKernelGGL(k_scan, dim3(1), dim3(768), 0, stream, flag, a, P0, Ug, x1p);
    hipLaunchKernelGGL(k_logits, dim3(VP / 64), dim3(256), 0, stream, flag, x1p, lw, lb, d_out);
    hipLaunchKernelGGL(k_norm, dim3(S), dim3(512), 0, stream, flag, d_out);
}

// Round 12
// 441.381 us; speedup vs baseline: 1.1039x; 1.1039x over previous
//
#include <hip/hip_runtime.h>

#define S 128
#define N 32
#define D 300
#define DP 320
#define E 64
#define R 4
#define V 50000
#define VP 50048
#define ND 9600
#define KY 1504   // stacked K for P0 GEMM: 4*300 conv + 300 W0 + 4 pad
#define DPAD 304  // padded N rows for Bt matrices

typedef unsigned short ushortT;
typedef __attribute__((ext_vector_type(8))) short short8;
typedef __attribute__((ext_vector_type(4))) short short4v;
typedef __attribute__((ext_vector_type(4))) float floatx4;
typedef __attribute__((ext_vector_type(2))) _Float16 half2v;
typedef __attribute__((ext_vector_type(13))) unsigned int uintx13;  // SSA vector: never memory

#if defined(__has_builtin)
#if __has_builtin(__builtin_amdgcn_fdot2)
#define HAVE_FDOT2 1
#endif
#if __has_builtin(__builtin_amdgcn_cvt_pkrtz)
#define HAVE_PKRTZ 1
#endif
#endif

__device__ inline float bf2f(ushortT h) {
    unsigned u = ((unsigned)h) << 16;
    float f;
    __builtin_memcpy(&f, &u, 4);
    return f;
}

__device__ inline float bfbits_lo(unsigned u) {
    unsigned b = u << 16;
    float f;
    __builtin_memcpy(&f, &b, 4);
    return f;
}

__device__ inline float bfbits_hi(unsigned u) {
    unsigned b = u & 0xffff0000u;
    float f;
    __builtin_memcpy(&f, &b, 4);
    return f;
}

__device__ inline ushortT f2bf(float f) {
    unsigned u;
    __builtin_memcpy(&u, &f, 4);
    unsigned r = (u + 0x7fffu + ((u >> 16) & 1u)) >> 16;
    return (ushortT)r;
}

__device__ inline float ldf(const void* p, size_t i, int isb) {
    return isb ? bf2f(((const ushortT*)p)[i]) : ((const float*)p)[i];
}

__device__ inline float rdlane(float v, int l) {
    int iv;
    __builtin_memcpy(&iv, &v, 4);
    int r = __builtin_amdgcn_readlane(iv, l);
    float f;
    __builtin_memcpy(&f, &r, 4);
    return f;
}

// packed-f16-pair dot with f32 accumulate: c += a.x*b.x + a.y*b.y
__device__ inline float dot2f(unsigned a, unsigned b, float c) {
    half2v av, bv;
    __builtin_memcpy(&av, &a, 4);
    __builtin_memcpy(&bv, &b, 4);
#if defined(HAVE_FDOT2)
    return __builtin_amdgcn_fdot2(av, bv, c, false);
#else
    return fmaf((float)av[1], (float)bv[1], fmaf((float)av[0], (float)bv[0], c));
#endif
}

__device__ inline unsigned packh2(float lo, float hi) {
    half2v h;
    h[0] = (_Float16)lo;
    h[1] = (_Float16)hi;
    unsigned u;
    __builtin_memcpy(&u, &h, 4);
    return u;
}

// pack two f32 -> packed f16 pair in ONE VALU op where available.
// NOTE (round-11 compile fix): cvt_pkrtz returns __fp16x2, not _Float16x2;
// capture with auto and bit-copy — the 4-byte pattern is what we want.
__device__ inline unsigned pk2(float lo, float hi) {
#if defined(HAVE_PKRTZ)
    auto h = __builtin_amdgcn_cvt_pkrtz(lo, hi);
    unsigned u;
    __builtin_memcpy(&u, &h, 4);
    return u;
#else
    return packh2(lo, hi);
#endif
}

// ---------------- K_detect: decide input dtype ------------------------------
__global__ void k_detect(const void* X, int* flag) {
    __shared__ int bad;
    if (threadIdx.x == 0) bad = 0;
    __syncthreads();
    const ushortT* p = (const ushortT*)X;
    int b = 0;
    for (int i = threadIdx.x; i < 4096; i += 256) {
        float v = bf2f(p[i]);
        if (!(v > -2.f && v < 2.f)) b = 1;  // catches NaN/Inf too
    }
    if (b) atomicOr(&bad, 1);
    __syncthreads();
    if (threadIdx.x == 0) flag[0] = bad ? 0 : 1;
}

// ---------------- K_prep: fused weight transposes (twg | tws) ---------------
__global__ void k_prep(const int* __restrict__ flag, const void* __restrict__ Wg,
                       const void* __restrict__ convW, const void* __restrict__ W0,
                       ushortT* __restrict__ wgt, ushortT* __restrict__ wst) {
    int isb = flag[0];
    __shared__ float tile[32][33];
    int bx = blockIdx.x;
    int d0 = blockIdx.y * 32;
    int tx = threadIdx.x & 31, ty = threadIdx.x >> 5;  // 32x8
    if (bx < ND / 32) {  // twg role
        int k0 = bx * 32;
        for (int i = ty; i < 32; i += 8) {
            int d = d0 + tx;
            tile[i][tx] = (d < D) ? ldf(Wg, (size_t)(k0 + i) * D + d, isb) : 0.f;
        }
        __syncthreads();
        for (int i = ty; i < 32; i += 8) {
            int d = d0 + i;
            if (d < DPAD) wgt[(size_t)d * ND + k0 + tx] = f2bf(tile[tx][i]);
        }
    } else {  // tws role
        int k0 = (bx - ND / 32) * 32;
        for (int i = ty; i < 32; i += 8) {
            int kp = k0 + i, d = d0 + tx;
            float v = 0.f;
            if (d < D && kp < 1500)
                v = (kp < 1200) ? ldf(convW, (size_t)kp * D + d, isb)
                                : ldf(W0, (size_t)(kp - 1200) * D + d, isb);
            tile[i][tx] = v;
        }
        __syncthreads();
        for (int i = ty; i < 32; i += 8) {
            int d = d0 + i;
            if (d < DPAD) wst[(size_t)d * KY + k0 + tx] = f2bf(tile[tx][i]);
        }
    }
}

// ---------------- K_gyb: fused gather (block's 32 rows) + yb build ----------
__global__ void k_gyb(const int* __restrict__ flag, const int* __restrict__ xi,
                      const void* __restrict__ X, const int* __restrict__ ei,
                      const int* __restrict__ et, ushortT* __restrict__ gxb,
                      ushortT* __restrict__ yb) {
    int isb = flag[0];
    int s = blockIdx.x;
    int t = threadIdx.x;  // 320
    __shared__ ushortT gl[N][D];  // 19.2 KB
    __shared__ int se[E], de[E], te[E];
    __shared__ float disv[R][N];
    if (t < E) {
        se[t] = ei[(size_t)s * 2 * E + t];
        de[t] = ei[(size_t)s * 2 * E + E + t];
        te[t] = et[(size_t)s * E + t];
    }
    if (t < D) {
#pragma unroll 4
        for (int r = 0; r < N; ++r) {
            int node = xi[s * N + r];
            ushortT v = isb ? ((const ushortT*)X)[(size_t)node * D + t]
                            : f2bf(((const float*)X)[(size_t)node * D + t]);
            gl[r][t] = v;
            gxb[(size_t)(s * N + r) * D + t] = v;
        }
    }
    __syncthreads();
    if (t < R * N) {
        int r = t >> 5, n = t & 31;
        float c = 1.f;
        for (int e = 0; e < E; ++e) c += (te[e] == r && de[e] == n) ? 1.f : 0.f;
        disv[r][n] = rsqrtf(c);
    }
    __syncthreads();
    if (t < D) {
        float g0 = bf2f(gl[0][t]);
        float yy[R];
#pragma unroll
        for (int r = 0; r < R; ++r) yy[r] = g0 * disv[r][0] * disv[r][0];
        for (int e = 0; e < E; ++e) {
            if (de[e] == 0) {
                int r = te[e];
                yy[r] += disv[r][se[e]] * disv[r][0] * bf2f(gl[se[e]][t]);
            }
        }
#pragma unroll
        for (int r = 0; r < R; ++r) yb[(size_t)s * KY + r * D + t] = f2bf(yy[r]);
        yb[(size_t)s * KY + 4 * D + t] = gl[0][t];  // gx0 slot for W0
    }
    if (t < 4) yb[(size_t)s * KY + 1500 + t] = 0;
}

// ---------------- K_gemm2: both GEMMs in one launch (z-encoded) -------------
__global__ __launch_bounds__(256) void k_gemm2(const ushortT* __restrict__ gxb,
                                               const ushortT* __restrict__ wgt,
                                               const ushortT* __restrict__ yb,
                                               const ushortT* __restrict__ wst,
                                               float* __restrict__ apart,
                                               float* __restrict__ ppart, int nza, int nzp) {
    int wave = threadIdx.x >> 6, lane = threadIdx.x & 63;
    int col = lane & 15, quad = lane >> 4;
    int m0 = blockIdx.x * 16, n0 = blockIdx.y * 16;
    int z = blockIdx.z;
    const ushortT *A, *Bt;
    float* C;
    int ld, kchunks, per, zz;
    if (z < nza) {
        A = gxb; Bt = wgt; C = apart; ld = ND; kchunks = ND / 32;
        zz = z; per = (kchunks + nza - 1) / nza;
    } else {
        A = yb; Bt = wst; C = ppart; ld = KY; kchunks = KY / 32;
        zz = z - nza; per = (kchunks + nzp - 1) / nzp;
    }
    int kbeg = zz * per;
    int kend = kbeg + per;
    if (kend > kchunks) kend = kchunks;
    floatx4 acc = {0.f, 0.f, 0.f, 0.f};
    const ushortT* ap = A + (size_t)(m0 + col) * ld + quad * 8;
    const ushortT* bp = Bt + (size_t)(n0 + col) * ld + quad * 8;
    for (int kc = kbeg + wave; kc < kend; kc += 4) {
        short8 a = *(const short8*)(ap + kc * 32);
        short8 b = *(const short8*)(bp + kc * 32);
        acc = __builtin_amdgcn_mfma_f32_16x16x32_bf16(a, b, acc, 0, 0, 0);
    }
    __shared__ float red[4][64][4];
#pragma unroll
    for (int i = 0; i < 4; ++i) red[wave][lane][i] = acc[i];
    __syncthreads();
    if (wave == 0) {
#pragma unroll
        for (int i = 0; i < 4; ++i) {
            float v = red[0][lane][i] + red[1][lane][i] + red[2][lane][i] + red[3][lane][i];
            int m = m0 + quad * 4 + i;
            int n = n0 + col;
            if (n < D) C[(size_t)zz * S * D + (size_t)m * D + n] = v;
        }
    }
}

// ---------------- K_red2: bulk z-reduce for BOTH partial arrays -------------
__global__ void k_red2(const float* __restrict__ apart, const float* __restrict__ ppart,
                       float* __restrict__ a, float* __restrict__ P0, int nza, int nzp) {
    int i = blockIdx.x * 256 + threadIdx.x;
    if (i < S * D) {
        float v = 0.f;
        for (int z = 0; z < nza; ++z) v += apart[(size_t)z * S * D + i];
        a[i] = v;
        float w = 0.f;
        for (int z = 0; z < nzp; ++z) w += ppart[(size_t)z * S * D + i];
        P0[i] = w;
    }
}

// ---------------- K6 v11b: scan, DS-op diet (LDS-throughput theory) ---------
// Round-11 was a compile fix only (cvt_pkrtz return type); experiment intact.
// Round-10 re-audit: the LDS unit is ONE per CU shared by all 12 waves, and
// v9 issues ~30 DS ops/wave/step -> 12x30x5.8 ~ 2100cy/step ~ measured 2300.
// The scan is LDS-OP-THROUGHPUT-bound.  v11 cuts DS to ~12/wave on v9 base:
//   - m-broadcast via v_readlane + cvt_pkrtz: wave w's reduce lanes 0..24
//     hold its window's m in mreg; MV[j] = pk2(rdlane(mreg,2j),
//     rdlane(mreg,2j+1)).  Kills 13 ds_reads + 1 ds_write + msh16 entirely;
//     costs 39 VALU/wave which runs per-SIMD in parallel, off the LDS unit.
//     (j=12 hi reads lane 25: mreg=0 there forever, matching the UV j=12 hi
//     mask -> doubly safe.)
//   - group-split reduce: lanes 0..24 sum partials w2=0..5, lanes 32..56 sum
//     w2=6..11 for the same myk; combine with one __shfl_xor(.,32).  12 DS
//     reads -> 6 + 1 bpermute, and the serial read chain halves.
//   - keep: 5 conflict-free part writes, part[2][12][320] double-buffer, raw
//     lgkmcnt-only barrier (v9-proven), a/P0 one-step prefetch, wpe(2,2)/768.
__global__ __attribute__((amdgpu_flat_work_group_size(768, 768), amdgpu_waves_per_eu(2, 2))) void
k_scan(const int* __restrict__ flag, const float* __restrict__ a, const float* __restrict__ P0,
       const void* __restrict__ Ug, ushortT* __restrict__ x1p) {
    int isb = flag[0];
    int t = threadIdx.x;
    int w = t >> 6, lane = t & 63;  // w 0..11
    int g = lane >> 5, l = lane & 31;
    int kbase = w * 25;             // 12*25 = 300 exact
    int myk = kbase + l;            // reduce lane's k (and output d)
    bool rok = l < 25;              // both groups read partials
    bool ep = rok && (g == 0);      // epilogue lanes (own mreg)
    int d4 = 256 + lane;
    bool d4ok = d4 < D;  // only the p=4 d-slice can exceed D
    // UVp[j] = packed (Ug[k1][dp], Ug[k2][dp]); k1=kbase+2j, k2=k1+1, j=0..12.
    uintx13 UV0, UV1, UV2, UV3, UV4;
#pragma unroll
    for (int j = 0; j < 13; ++j) {
        int k1 = kbase + 2 * j, k2 = k1 + 1;
        bool k2ok = (2 * j + 1) < 25;
        UV0[j] = packh2(ldf(Ug, (size_t)k1 * D + lane, isb),
                        k2ok ? ldf(Ug, (size_t)k2 * D + lane, isb) : 0.f);
        UV1[j] = packh2(ldf(Ug, (size_t)k1 * D + 64 + lane, isb),
                        k2ok ? ldf(Ug, (size_t)k2 * D + 64 + lane, isb) : 0.f);
        UV2[j] = packh2(ldf(Ug, (size_t)k1 * D + 128 + lane, isb),
                        k2ok ? ldf(Ug, (size_t)k2 * D + 128 + lane, isb) : 0.f);
        UV3[j] = packh2(ldf(Ug, (size_t)k1 * D + 192 + lane, isb),
                        k2ok ? ldf(Ug, (size_t)k2 * D + 192 + lane, isb) : 0.f);
        UV4[j] = packh2(d4ok ? ldf(Ug, (size_t)k1 * D + d4, isb) : 0.f,
                        (k2ok && d4ok) ? ldf(Ug, (size_t)k2 * D + d4, isb) : 0.f);
    }
    // zero x1p pad columns [300,320) once (disjoint from step writes)
    for (int i = t; i < S * 20; i += 768) {
        int s = i / 20, d = 300 + (i % 20);
        x1p[(size_t)s * DP + d] = 0;
    }
    __shared__ float part[2][12][320];  // double-buffered wave partials (30.7 KB)
    float mreg = 0.f;  // m[myk] in ep lanes; 0 everywhere else forever
    int buf = 0;
    float av = 0.f, pv = 0.f;
    if (ep) {
        av = a[myk];
        pv = P0[myk];
    }
    __syncthreads();
    for (int s = 0; s < S; ++s) {
        // prefetch NEXT step's a/P0 (stays in flight across the raw barrier)
        float avn = 0.f, pvn = 0.f;
        if (ep && s + 1 < S) {
            avn = a[(size_t)(s + 1) * D + myk];
            pvn = P0[(size_t)(s + 1) * D + myk];
        }
        // m-broadcast from own wave's ep lanes: no LDS traffic
        uintx13 MV;
#pragma unroll
        for (int j = 0; j < 13; ++j)
            MV[j] = pk2(rdlane(mreg, 2 * j), rdlane(mreg, 2 * j + 1));
        float acc0 = 0.f, acc1 = 0.f, acc2 = 0.f, acc3 = 0.f, acc4 = 0.f;
#pragma unroll
        for (int j = 0; j < 13; ++j) {
            unsigned md = MV[j];
            acc0 = dot2f(UV0[j], md, acc0);
            acc1 = dot2f(UV1[j], md, acc1);
            acc2 = dot2f(UV2[j], md, acc2);
            acc3 = dot2f(UV3[j], md, acc3);
            acc4 = dot2f(UV4[j], md, acc4);
        }
        part[buf][w][lane] = acc0;
        part[buf][w][64 + lane] = acc1;
        part[buf][w][128 + lane] = acc2;
        part[buf][w][192 + lane] = acc3;
        part[buf][w][256 + lane] = acc4;
        // raw barrier: DS-only drain; vmcnt ops stay in flight (v9-proven)
        __builtin_amdgcn_sched_barrier(0);
        asm volatile("s_waitcnt lgkmcnt(0)" ::: "memory");
        __builtin_amdgcn_s_barrier();
        __builtin_amdgcn_sched_barrier(0);
        // group-split reduce: g=0 sums w2 0..5, g=1 sums w2 6..11 (same myk)
        float sum6 = 0.f;
        if (rok) {
            const float* pb = &part[buf][0][0];
            int wb = g * 6;
            float q0 = pb[(wb + 0) * 320 + myk] + pb[(wb + 1) * 320 + myk];
            float q1 = pb[(wb + 2) * 320 + myk] + pb[(wb + 3) * 320 + myk];
            float q2 = pb[(wb + 4) * 320 + myk] + pb[(wb + 5) * 320 + myk];
            sum6 = (q0 + q1) + q2;
        }
        float other = __shfl_xor(sum6, 32, 64);
        if (ep) {
            float pr = av + sum6 + other;
            float u = 1.f / (1.f + __expf(-pr));
            float nm = u * pv + (1.f - u) * mreg;
            mreg = nm;
            float x = nm > 0.f ? nm : 0.01f * nm;
            x1p[(size_t)s * DP + myk] = f2bf(x);
        }
        av = avn;
        pv = pvn;
        buf ^= 1;
    }
}

// ---------------- K7: logits = x1 @ lin_w^T + b via MFMA --------------------
__global__ __launch_bounds__(256) void k_logits(const int* __restrict__ flag,
                                                const ushortT* __restrict__ x1p,
                                                const void* __restrict__ lw,
                                                const void* __restrict__ lb,
                                                void* __restrict__ out) {
    int isb = flag[0];
    int wave = threadIdx.x >> 6, lane = threadIdx.x & 63;
    int col = lane & 15, quad = lane >> 4;
    int v = blockIdx.x * 64 + wave * 16 + col;
    int vv = v < V ? v : V - 1;
    floatx4 acc[8];
#pragma unroll
    for (int i = 0; i < 8; ++i) acc[i] = (floatx4){0.f, 0.f, 0.f, 0.f};
#pragma unroll
    for (int kc = 0; kc < 9; ++kc) {
        int k0 = kc * 32 + quad * 8;
        short8 b;
        if (isb) {
            const ushortT* bp = (const ushortT*)lw + (size_t)vv * D + k0;  // 8B aligned
            short4v lo = *(const short4v*)bp;
            short4v hi = *(const short4v*)(bp + 4);
            b = (short8){lo[0], lo[1], lo[2], lo[3], hi[0], hi[1], hi[2], hi[3]};
        } else {
            const float* bp = (const float*)lw + (size_t)vv * D + k0;  // 16B aligned
            floatx4 f0 = *(const floatx4*)bp;
            floatx4 f1 = *(const floatx4*)(bp + 4);
            b = (short8){(short)f2bf(f0[0]), (short)f2bf(f0[1]), (short)f2bf(f0[2]),
                         (short)f2bf(f0[3]), (short)f2bf(f1[0]), (short)f2bf(f1[1]),
                         (short)f2bf(f1[2]), (short)f2bf(f1[3])};
        }
#pragma unroll
        for (int st = 0; st < 8; ++st) {
            short8 aa = *(const short8*)(x1p + (size_t)(st * 16 + col) * DP + k0);
            acc[st] = __builtin_amdgcn_mfma_f32_16x16x32_bf16(aa, b, acc[st], 0, 0, 0);
        }
    }
    {  // tail chunk k=288..319 (lin_w valid only k<300; x1p zero-padded)
        int k0 = 288 + quad * 8;
        short8 b;
#pragma unroll
        for (int j = 0; j < 8; ++j) {
            int k = k0 + j;
            ushortT bv = 0;
            if (k < D)
                bv = isb ? ((const ushortT*)lw)[(size_t)vv * D + k]
                         : f2bf(((const float*)lw)[(size_t)vv * D + k]);
            b[j] = (short)bv;
        }
#pragma unroll
        for (int st = 0; st < 8; ++st) {
            short8 aa = *(const short8*)(x1p + (size_t)(st * 16 + col) * DP + k0);
            acc[st] = __builtin_amdgcn_mfma_f32_16x16x32_bf16(aa, b, acc[st], 0, 0, 0);
        }
    }
    if (v < V) {
        float bias = ldf(lb, v, isb);
#pragma unroll
        for (int st = 0; st < 8; ++st) {
#pragma unroll
            for (int i = 0; i < 4; ++i) {
                int s = st * 16 + quad * 4 + i;
                float val = acc[st][i] + bias;
                if (isb)
                    ((ushortT*)out)[(size_t)s * V + v] = f2bf(val);
                else
                    ((float*)out)[(size_t)s * V + v] = val;
            }
        }
    }
}

// ---------------- K8: fused logsumexp + in-place normalize + senses tail ----
__global__ __launch_bounds__(512) void k_norm(const int* __restrict__ flag,
                                              void* __restrict__ out) {
    int isb = flag[0];
    int s = blockIdx.x;
    int t = threadIdx.x;
    __shared__ float red[512];
    if (s == 0 && t < S) {
        if (isb)
            ((ushortT*)out)[(size_t)S * V + t] = 0;
        else
            ((float*)out)[(size_t)S * V + t] = 0.f;
    }
    float mx = -1e30f;
    if (isb) {
        const uint4* row = (const uint4*)((const ushortT*)out + (size_t)s * V);  // 6250 vecs
        for (int i = t; i < 6250; i += 512) {
            uint4 q = row[i];
            mx = fmaxf(mx, fmaxf(fmaxf(bfbits_lo(q.x), bfbits_hi(q.x)),
                                 fmaxf(bfbits_lo(q.y), bfbits_hi(q.y))));
            mx = fmaxf(mx, fmaxf(fmaxf(bfbits_lo(q.z), bfbits_hi(q.z)),
                                 fmaxf(bfbits_lo(q.w), bfbits_hi(q.w))));
        }
    } else {
        const floatx4* row = (const floatx4*)((const float*)out + (size_t)s * V);  // 12500 vecs
        for (int i = t; i < 12500; i += 512) {
            floatx4 q = row[i];
            mx = fmaxf(mx, fmaxf(fmaxf(q[0], q[1]), fmaxf(q[2], q[3])));
        }
    }
    red[t] = mx;
    __syncthreads();
    for (int o = 256; o > 0; o >>= 1) {
        if (t < o) red[t] = fmaxf(red[t], red[t + o]);
        __syncthreads();
    }
    float M = red[0];
    __syncthreads();
    float sm = 0.f;
    if (isb) {
        const uint4* row = (const uint4*)((const ushortT*)out + (size_t)s * V);
        for (int i = t; i < 6250; i += 512) {
            uint4 q = row[i];
            sm += __expf(bfbits_lo(q.x) - M) + __expf(bfbits_hi(q.x) - M) +
                  __expf(bfbits_lo(q.y) - M) + __expf(bfbits_hi(q.y) - M) +
                  __expf(bfbits_lo(q.z) - M) + __expf(bfbits_hi(q.z) - M) +
                  __expf(bfbits_lo(q.w) - M) + __expf(bfbits_hi(q.w) - M);
        }
    } else {
        const floatx4* row = (const floatx4*)((const float*)out + (size_t)s * V);
        for (int i = t; i < 12500; i += 512) {
            floatx4 q = row[i];
            sm += __expf(q[0] - M) + __expf(q[1] - M) + __expf(q[2] - M) + __expf(q[3] - M);
        }
    }
    red[t] = sm;
    __syncthreads();
    for (int o = 256; o > 0; o >>= 1) {
        if (t < o) red[t] += red[t + o];
        __syncthreads();
    }
    float lse = M + __logf(red[0]);
    if (isb) {
        uint4* row = (uint4*)((ushortT*)out + (size_t)s * V);
        for (int i = t; i < 6250; i += 512) {
            uint4 q = row[i];
            uint4 o;
            o.x = (unsigned)f2bf(bfbits_lo(q.x) - lse) |
                  ((unsigned)f2bf(bfbits_hi(q.x) - lse) << 16);
            o.y = (unsigned)f2bf(bfbits_lo(q.y) - lse) |
                  ((unsigned)f2bf(bfbits_hi(q.y) - lse) << 16);
            o.z = (unsigned)f2bf(bfbits_lo(q.z) - lse) |
                  ((unsigned)f2bf(bfbits_hi(q.z) - lse) << 16);
            o.w = (unsigned)f2bf(bfbits_lo(q.w) - lse) |
                  ((unsigned)f2bf(bfbits_hi(q.w) - lse) << 16);
            row[i] = o;
        }
    } else {
        floatx4* row = (floatx4*)((float*)out + (size_t)s * V);
        for (int i = t; i < 12500; i += 512) {
            floatx4 q = row[i];
            q[0] -= lse;
            q[1] -= lse;
            q[2] -= lse;
            q[3] -= lse;
            row[i] = q;
        }
    }
}

// ---------------- workspace layout (bytes, all 256-aligned) -----------------
#define OFF_FLAG 0
#define OFF_GXB 256
#define OFF_WGT 2457856
#define OFF_WST 8294656
#define OFF_YB 9209088
#define OFF_A 9594112
#define OFF_P0 9747712
#define OFF_X1P 9901312
#define OFF_STATS 9983232
#define OFF_PART 9983744  // optional z-split partial buffers (needs bigger ws)
#define PART_A_BYTES (4 * S * D * 4)
#define PART_P_BYTES (2 * S * D * 4)

extern "C" void kernel_launch(void* const* d_in, const int* in_sizes, int n_in, void* d_out,
                              int out_size, void* d_ws, size_t ws_size, hipStream_t stream) {
    const int* xi = (const int*)d_in[0];
    const int* ei = (const int*)d_in[1];
    const int* et = (const int*)d_in[2];
    const void* X = d_in[3];
    const void* convW = d_in[4];
    const void* W0 = d_in[5];
    const void* Wg = d_in[6];
    const void* Ug = d_in[7];
    const void* lw = d_in[8];
    const void* lb = d_in[9];
    char* ws = (char*)d_ws;

    int* flag = (int*)(ws + OFF_FLAG);
    ushortT* gxb = (ushortT*)(ws + OFF_GXB);
    ushortT* wgt = (ushortT*)(ws + OFF_WGT);
    ushortT* wst = (ushortT*)(ws + OFF_WST);
    ushortT* yb = (ushortT*)(ws + OFF_YB);
    float* a = (float*)(ws + OFF_A);
    float* P0 = (float*)(ws + OFF_P0);
    ushortT* x1p = (ushortT*)(ws + OFF_X1P);

    // z-split K only if workspace is big enough for partial buffers
    bool split = ws_size >= (size_t)(OFF_PART + PART_A_BYTES + PART_P_BYTES);
    int nza = split ? 4 : 1;
    int nzp = split ? 2 : 1;
    float* apart = split ? (float*)(ws + OFF_PART) : a;
    float* ppart = split ? (float*)(ws + OFF_PART + PART_A_BYTES) : P0;

    hipLaunchKernelGGL(k_detect, dim3(1), dim3(256), 0, stream, X, flag);
    hipLaunchKernelGGL(k_prep, dim3(ND / 32 + KY / 32, 10), dim3(256), 0, stream, flag, Wg,
                       convW, W0, wgt, wst);
    hipLaunchKernelGGL(k_gyb, dim3(S), dim3(DP), 0, stream, flag, xi, X, ei, et, gxb, yb);
    hipLaunchKernelGGL(k_gemm2, dim3(S / 16, 19, nza + nzp), dim3(256), 0, stream, gxb, wgt,
                       yb, wst, apart, ppart, nza, nzp);
    if (split)
        hipLaunchKernelGGL(k_red2, dim3((S * D + 255) / 256), dim3(256), 0, stream, apart,
                           ppart, a, P0, nza, nzp);
    hipLaunchKernelGGL(k_scan, dim3(1), dim3(768), 0, stream, flag, a, P0, Ug, x1p);
    hipLaunchKernelGGL(k_logits, dim3(VP / 64), dim3(256), 0, stream, flag, x1p, lw, lb, d_out);
    hipLaunchKernelGGL(k_norm, dim3(S), dim3(512), 0, stream, flag, d_out);
}

// Round 13
// 421.124 us; speedup vs baseline: 1.1570x; 1.0481x over previous
//
#include <hip/hip_runtime.h>

#define S 128
#define N 32
#define D 300
#define DP 320
#define E 64
#define R 4
#define V 50000
#define VP 50048
#define ND 9600
#define KY 1504   // stacked K for P0 GEMM: 4*300 conv + 300 W0 + 4 pad
#define DPAD 304  // padded N rows for Bt matrices

typedef unsigned short ushortT;
typedef __attribute__((ext_vector_type(8))) short short8;
typedef __attribute__((ext_vector_type(4))) short short4v;
typedef __attribute__((ext_vector_type(4))) float floatx4;
typedef __attribute__((ext_vector_type(4))) unsigned int uint4v;
typedef __attribute__((ext_vector_type(2))) _Float16 half2v;
typedef __attribute__((ext_vector_type(13))) unsigned int uintx13;  // SSA vector: never memory

#if defined(__has_builtin)
#if __has_builtin(__builtin_amdgcn_fdot2)
#define HAVE_FDOT2 1
#endif
#endif

__device__ inline float bf2f(ushortT h) {
    unsigned u = ((unsigned)h) << 16;
    float f;
    __builtin_memcpy(&f, &u, 4);
    return f;
}

__device__ inline float bfbits_lo(unsigned u) {
    unsigned b = u << 16;
    float f;
    __builtin_memcpy(&f, &b, 4);
    return f;
}

__device__ inline float bfbits_hi(unsigned u) {
    unsigned b = u & 0xffff0000u;
    float f;
    __builtin_memcpy(&f, &b, 4);
    return f;
}

__device__ inline ushortT f2bf(float f) {
    unsigned u;
    __builtin_memcpy(&u, &f, 4);
    unsigned r = (u + 0x7fffu + ((u >> 16) & 1u)) >> 16;
    return (ushortT)r;
}

__device__ inline float ldf(const void* p, size_t i, int isb) {
    return isb ? bf2f(((const ushortT*)p)[i]) : ((const float*)p)[i];
}

// packed-f16-pair dot with f32 accumulate: c += a.x*b.x + a.y*b.y
__device__ inline float dot2f(unsigned a, unsigned b, float c) {
    half2v av, bv;
    __builtin_memcpy(&av, &a, 4);
    __builtin_memcpy(&bv, &b, 4);
#if defined(HAVE_FDOT2)
    return __builtin_amdgcn_fdot2(av, bv, c, false);
#else
    return fmaf((float)av[1], (float)bv[1], fmaf((float)av[0], (float)bv[0], c));
#endif
}

__device__ inline unsigned packh2(float lo, float hi) {
    half2v h;
    h[0] = (_Float16)lo;
    h[1] = (_Float16)hi;
    unsigned u;
    __builtin_memcpy(&u, &h, 4);
    return u;
}

// ---------------- K_detect: decide input dtype ------------------------------
__global__ void k_detect(const void* X, int* flag) {
    __shared__ int bad;
    if (threadIdx.x == 0) bad = 0;
    __syncthreads();
    const ushortT* p = (const ushortT*)X;
    int b = 0;
    for (int i = threadIdx.x; i < 4096; i += 256) {
        float v = bf2f(p[i]);
        if (!(v > -2.f && v < 2.f)) b = 1;  // catches NaN/Inf too
    }
    if (b) atomicOr(&bad, 1);
    __syncthreads();
    if (threadIdx.x == 0) flag[0] = bad ? 0 : 1;
}

// ---------------- K_prep: fused weight transposes (twg | tws) ---------------
__global__ void k_prep(const int* __restrict__ flag, const void* __restrict__ Wg,
                       const void* __restrict__ convW, const void* __restrict__ W0,
                       ushortT* __restrict__ wgt, ushortT* __restrict__ wst) {
    int isb = flag[0];
    __shared__ float tile[32][33];
    int bx = blockIdx.x;
    int d0 = blockIdx.y * 32;
    int tx = threadIdx.x & 31, ty = threadIdx.x >> 5;  // 32x8
    if (bx < ND / 32) {  // twg role
        int k0 = bx * 32;
        for (int i = ty; i < 32; i += 8) {
            int d = d0 + tx;
            tile[i][tx] = (d < D) ? ldf(Wg, (size_t)(k0 + i) * D + d, isb) : 0.f;
        }
        __syncthreads();
        for (int i = ty; i < 32; i += 8) {
            int d = d0 + i;
            if (d < DPAD) wgt[(size_t)d * ND + k0 + tx] = f2bf(tile[tx][i]);
        }
    } else {  // tws role
        int k0 = (bx - ND / 32) * 32;
        for (int i = ty; i < 32; i += 8) {
            int kp = k0 + i, d = d0 + tx;
            float v = 0.f;
            if (d < D && kp < 1500)
                v = (kp < 1200) ? ldf(convW, (size_t)kp * D + d, isb)
                                : ldf(W0, (size_t)(kp - 1200) * D + d, isb);
            tile[i][tx] = v;
        }
        __syncthreads();
        for (int i = ty; i < 32; i += 8) {
            int d = d0 + i;
            if (d < DPAD) wst[(size_t)d * KY + k0 + tx] = f2bf(tile[tx][i]);
        }
    }
}

// ---------------- K_gyb: fused gather (block's 32 rows) + yb build ----------
__global__ void k_gyb(const int* __restrict__ flag, const int* __restrict__ xi,
                      const void* __restrict__ X, const int* __restrict__ ei,
                      const int* __restrict__ et, ushortT* __restrict__ gxb,
                      ushortT* __restrict__ yb) {
    int isb = flag[0];
    int s = blockIdx.x;
    int t = threadIdx.x;  // 320
    __shared__ ushortT gl[N][D];  // 19.2 KB
    __shared__ int se[E], de[E], te[E];
    __shared__ float disv[R][N];
    if (t < E) {
        se[t] = ei[(size_t)s * 2 * E + t];
        de[t] = ei[(size_t)s * 2 * E + E + t];
        te[t] = et[(size_t)s * E + t];
    }
    if (t < D) {
#pragma unroll 4
        for (int r = 0; r < N; ++r) {
            int node = xi[s * N + r];
            ushortT v = isb ? ((const ushortT*)X)[(size_t)node * D + t]
                            : f2bf(((const float*)X)[(size_t)node * D + t]);
            gl[r][t] = v;
            gxb[(size_t)(s * N + r) * D + t] = v;
        }
    }
    __syncthreads();
    if (t < R * N) {
        int r = t >> 5, n = t & 31;
        float c = 1.f;
        for (int e = 0; e < E; ++e) c += (te[e] == r && de[e] == n) ? 1.f : 0.f;
        disv[r][n] = rsqrtf(c);
    }
    __syncthreads();
    if (t < D) {
        float g0 = bf2f(gl[0][t]);
        float yy[R];
#pragma unroll
        for (int r = 0; r < R; ++r) yy[r] = g0 * disv[r][0] * disv[r][0];
        for (int e = 0; e < E; ++e) {
            if (de[e] == 0) {
                int r = te[e];
                yy[r] += disv[r][se[e]] * disv[r][0] * bf2f(gl[se[e]][t]);
            }
        }
#pragma unroll
        for (int r = 0; r < R; ++r) yb[(size_t)s * KY + r * D + t] = f2bf(yy[r]);
        yb[(size_t)s * KY + 4 * D + t] = gl[0][t];  // gx0 slot for W0
    }
    if (t < 4) yb[(size_t)s * KY + 1500 + t] = 0;
}

// ---------------- K_gemm2: both GEMMs in one launch (z-encoded) -------------
__global__ __launch_bounds__(256) void k_gemm2(const ushortT* __restrict__ gxb,
                                               const ushortT* __restrict__ wgt,
                                               const ushortT* __restrict__ yb,
                                               const ushortT* __restrict__ wst,
                                               float* __restrict__ apart,
                                               float* __restrict__ ppart, int nza, int nzp) {
    int wave = threadIdx.x >> 6, lane = threadIdx.x & 63;
    int col = lane & 15, quad = lane >> 4;
    int m0 = blockIdx.x * 16, n0 = blockIdx.y * 16;
    int z = blockIdx.z;
    const ushortT *A, *Bt;
    float* C;
    int ld, kchunks, per, zz;
    if (z < nza) {
        A = gxb; Bt = wgt; C = apart; ld = ND; kchunks = ND / 32;
        zz = z; per = (kchunks + nza - 1) / nza;
    } else {
        A = yb; Bt = wst; C = ppart; ld = KY; kchunks = KY / 32;
        zz = z - nza; per = (kchunks + nzp - 1) / nzp;
    }
    int kbeg = zz * per;
    int kend = kbeg + per;
    if (kend > kchunks) kend = kchunks;
    floatx4 acc = {0.f, 0.f, 0.f, 0.f};
    const ushortT* ap = A + (size_t)(m0 + col) * ld + quad * 8;
    const ushortT* bp = Bt + (size_t)(n0 + col) * ld + quad * 8;
    for (int kc = kbeg + wave; kc < kend; kc += 4) {
        short8 a = *(const short8*)(ap + kc * 32);
        short8 b = *(const short8*)(bp + kc * 32);
        acc = __builtin_amdgcn_mfma_f32_16x16x32_bf16(a, b, acc, 0, 0, 0);
    }
    __shared__ float red[4][64][4];
#pragma unroll
    for (int i = 0; i < 4; ++i) red[wave][lane][i] = acc[i];
    __syncthreads();
    if (wave == 0) {
#pragma unroll
        for (int i = 0; i < 4; ++i) {
            float v = red[0][lane][i] + red[1][lane][i] + red[2][lane][i] + red[3][lane][i];
            int m = m0 + quad * 4 + i;
            int n = n0 + col;
            if (n < D) C[(size_t)zz * S * D + (size_t)m * D + n] = v;
        }
    }
}

// ---------------- K_red2: bulk z-reduce for BOTH partial arrays -------------
__global__ void k_red2(const float* __restrict__ apart, const float* __restrict__ ppart,
                       float* __restrict__ a, float* __restrict__ P0, int nza, int nzp) {
    int i = blockIdx.x * 256 + threadIdx.x;
    if (i < S * D) {
        float v = 0.f;
        for (int z = 0; z < nza; ++z) v += apart[(size_t)z * S * D + i];
        a[i] = v;
        float w = 0.f;
        for (int z = 0; z < nzp; ++z) w += ppart[(size_t)z * S * D + i];
        P0[i] = w;
    }
}

// ---------------- K6 v12: v9 scan + FORCED UV register residency ------------
// Round-12 post-mortem: v11b's readlane m-broadcast REGRESSED (140us, VALU
// 78% on-CU) -> LDS-throughput theory refuted; revert to v9's msh/reduce.
// The clue ignored since round 7: VGPR_Count=72 but UV state = 65 dwords +
// ~20 working regs.  It cannot fit -> the compiler either AGPR-parks or
// (worse, and consistent with the unexplained ~1500cy/step) SINKS the UV
// loads into the loop and re-fetches Ug from L2 EVERY STEP (invisible in
// FETCH_SIZE: L2 hits aren't HBM; invisible in VALUBusy: VMEM-wait).
// v12 forces residency: after the preload, launder every UV element through
// asm volatile("" : "+v") — provenance destroyed, rematerialization/reload
// impossible; values must stay live in registers (arch or AGPR, either beats
// an L2 round trip per use).  Falsifier: VGPR_Count must jump to >=130.
// Also: msh padded to stride-16 dwords/wave so the 13 m-broadcast reads
// batch as 3x ds_read_b128 + 1 (64B-aligned, broadcast, independent tweak).
__global__ __attribute__((amdgpu_flat_work_group_size(768, 768), amdgpu_waves_per_eu(2, 2))) void
k_scan(const int* __restrict__ flag, const float* __restrict__ a, const float* __restrict__ P0,
       const void* __restrict__ Ug, ushortT* __restrict__ x1p) {
    int isb = flag[0];
    int t = threadIdx.x;
    int w = t >> 6, lane = t & 63;  // w 0..11
    int kbase = w * 25;             // 12*25 = 300 exact
    int myk = kbase + lane;         // this lane's k (and output d) for the reduce
    bool red_ok = lane < 25;        // myk < 300 guaranteed
    int d4 = 256 + lane;
    bool d4ok = d4 < D;  // only the p=4 d-slice can exceed D
    // UVp[j] = packed (Ug[k1][dp], Ug[k2][dp]); k1=kbase+2j, k2=k1+1, j=0..12.
    uintx13 UV0, UV1, UV2, UV3, UV4;
#pragma unroll
    for (int j = 0; j < 13; ++j) {
        int k1 = kbase + 2 * j, k2 = k1 + 1;
        bool k2ok = (2 * j + 1) < 25;
        UV0[j] = packh2(ldf(Ug, (size_t)k1 * D + lane, isb),
                        k2ok ? ldf(Ug, (size_t)k2 * D + lane, isb) : 0.f);
        UV1[j] = packh2(ldf(Ug, (size_t)k1 * D + 64 + lane, isb),
                        k2ok ? ldf(Ug, (size_t)k2 * D + 64 + lane, isb) : 0.f);
        UV2[j] = packh2(ldf(Ug, (size_t)k1 * D + 128 + lane, isb),
                        k2ok ? ldf(Ug, (size_t)k2 * D + 128 + lane, isb) : 0.f);
        UV3[j] = packh2(ldf(Ug, (size_t)k1 * D + 192 + lane, isb),
                        k2ok ? ldf(Ug, (size_t)k2 * D + 192 + lane, isb) : 0.f);
        UV4[j] = packh2(d4ok ? ldf(Ug, (size_t)k1 * D + d4, isb) : 0.f,
                        (k2ok && d4ok) ? ldf(Ug, (size_t)k2 * D + d4, isb) : 0.f);
    }
    // FORCE residency: destroy provenance of every UV element (rule #17 tool).
#pragma unroll
    for (int j = 0; j < 13; ++j) {
        unsigned x0 = UV0[j], x1 = UV1[j], x2 = UV2[j], x3 = UV3[j], x4 = UV4[j];
        asm volatile("" : "+v"(x0), "+v"(x1), "+v"(x2), "+v"(x3), "+v"(x4));
        UV0[j] = x0;
        UV1[j] = x1;
        UV2[j] = x2;
        UV3[j] = x3;
        UV4[j] = x4;
    }
    // zero x1p pad columns [300,320) once (disjoint from step writes)
    for (int i = t; i < S * 20; i += 768) {
        int s = i / 20, d = 300 + (i % 20);
        x1p[(size_t)s * DP + d] = 0;
    }
    __shared__ float part[2][12][320];  // double-buffered wave partials (30.7 KB)
    __shared__ unsigned msh16[12 * 16]; // packed-f16 m; wave w owns dwords
                                        // [16w,16w+13) (25 m halves + pads);
                                        // stride 16 -> 64B-aligned b128 reads
    for (int i = t; i < 12 * 16; i += 768) msh16[i] = 0;
    float mreg = 0.f;  // m[myk]; lanes with !red_ok stay 0 forever
    int buf = 0;
    float av = 0.f, pv = 0.f;
    if (red_ok) {
        av = a[myk];
        pv = P0[myk];
    }
    __syncthreads();  // once: msh16 init visibility (cross-wave not needed, but cheap)
    for (int s = 0; s < S; ++s) {
        // prefetch NEXT step's a/P0 (stays in flight across the raw barrier)
        float avn = 0.f, pvn = 0.f;
        if (red_ok && s + 1 < S) {
            avn = a[(size_t)(s + 1) * D + myk];
            pvn = P0[(size_t)(s + 1) * D + myk];
        }
        // m-broadcast: wave-private dwords, batched as b128 x3 + b32
        uintx13 MV;
        {
            uint4v m0v = *(const uint4v*)&msh16[16 * w];
            uint4v m1v = *(const uint4v*)&msh16[16 * w + 4];
            uint4v m2v = *(const uint4v*)&msh16[16 * w + 8];
            MV[0] = m0v[0]; MV[1] = m0v[1]; MV[2] = m0v[2]; MV[3] = m0v[3];
            MV[4] = m1v[0]; MV[5] = m1v[1]; MV[6] = m1v[2]; MV[7] = m1v[3];
            MV[8] = m2v[0]; MV[9] = m2v[1]; MV[10] = m2v[2]; MV[11] = m2v[3];
            MV[12] = msh16[16 * w + 12];
        }
        float acc0 = 0.f, acc1 = 0.f, acc2 = 0.f, acc3 = 0.f, acc4 = 0.f;
#pragma unroll
        for (int j = 0; j < 13; ++j) {
            unsigned md = MV[j];
            acc0 = dot2f(UV0[j], md, acc0);
            acc1 = dot2f(UV1[j], md, acc1);
            acc2 = dot2f(UV2[j], md, acc2);
            acc3 = dot2f(UV3[j], md, acc3);
            acc4 = dot2f(UV4[j], md, acc4);
        }
        part[buf][w][lane] = acc0;
        part[buf][w][64 + lane] = acc1;
        part[buf][w][128 + lane] = acc2;
        part[buf][w][192 + lane] = acc3;
        part[buf][w][256 + lane] = acc4;
        // raw barrier: DS-only drain; vmcnt ops stay in flight (v9-proven)
        __builtin_amdgcn_sched_barrier(0);
        asm volatile("s_waitcnt lgkmcnt(0)" ::: "memory");
        __builtin_amdgcn_s_barrier();
        __builtin_amdgcn_sched_barrier(0);
        if (red_ok) {
            // pairwise tree over the 12 wave partials (loads issue in parallel)
            float q0 = part[buf][0][myk] + part[buf][1][myk];
            float q1 = part[buf][2][myk] + part[buf][3][myk];
            float q2 = part[buf][4][myk] + part[buf][5][myk];
            float q3 = part[buf][6][myk] + part[buf][7][myk];
            float q4 = part[buf][8][myk] + part[buf][9][myk];
            float q5 = part[buf][10][myk] + part[buf][11][myk];
            float pr = av + (((q0 + q1) + (q2 + q3)) + (q4 + q5));
            float u = 1.f / (1.f + __expf(-pr));
            float nm = u * pv + (1.f - u) * mreg;
            mreg = nm;
            _Float16 mh = (_Float16)nm;
            ushortT mb;
            __builtin_memcpy(&mb, &mh, 2);
            ((ushortT*)msh16)[32 * w + lane] = mb;  // own wave's halves: no barrier
            float x = nm > 0.f ? nm : 0.01f * nm;
            x1p[(size_t)s * DP + myk] = f2bf(x);
        }
        av = avn;
        pv = pvn;
        buf ^= 1;
    }
}

// ---------------- K7: logits = x1 @ lin_w^T + b via MFMA --------------------
__global__ __launch_bounds__(256) void k_logits(const int* __restrict__ flag,
                                                const ushortT* __restrict__ x1p,
                                                const void* __restrict__ lw,
                                                const void* __restrict__ lb,
                                                void* __restrict__ out) {
    int isb = flag[0];
    int wave = threadIdx.x >> 6, lane = threadIdx.x & 63;
    int col = lane & 15, quad = lane >> 4;
    int v = blockIdx.x * 64 + wave * 16 + col;
    int vv = v < V ? v : V - 1;
    floatx4 acc[8];
#pragma unroll
    for (int i = 0; i < 8; ++i) acc[i] = (floatx4){0.f, 0.f, 0.f, 0.f};
#pragma unroll
    for (int kc = 0; kc < 9; ++kc) {
        int k0 = kc * 32 + quad * 8;
        short8 b;
        if (isb) {
            const ushortT* bp = (const ushortT*)lw + (size_t)vv * D + k0;  // 8B aligned
            short4v lo = *(const short4v*)bp;
            short4v hi = *(const short4v*)(bp + 4);
            b = (short8){lo[0], lo[1], lo[2], lo[3], hi[0], hi[1], hi[2], hi[3]};
        } else {
            const float* bp = (const float*)lw + (size_t)vv * D + k0;  // 16B aligned
            floatx4 f0 = *(const floatx4*)bp;
            floatx4 f1 = *(const floatx4*)(bp + 4);
            b = (short8){(short)f2bf(f0[0]), (short)f2bf(f0[1]), (short)f2bf(f0[2]),
                         (short)f2bf(f0[3]), (short)f2bf(f1[0]), (short)f2bf(f1[1]),
                         (short)f2bf(f1[2]), (short)f2bf(f1[3])};
        }
#pragma unroll
        for (int st = 0; st < 8; ++st) {
            short8 aa = *(const short8*)(x1p + (size_t)(st * 16 + col) * DP + k0);
            acc[st] = __builtin_amdgcn_mfma_f32_16x16x32_bf16(aa, b, acc[st], 0, 0, 0);
        }
    }
    {  // tail chunk k=288..319 (lin_w valid only k<300; x1p zero-padded)
        int k0 = 288 + quad * 8;
        short8 b;
#pragma unroll
        for (int j = 0; j < 8; ++j) {
            int k = k0 + j;
            ushortT bv = 0;
            if (k < D)
                bv = isb ? ((const ushortT*)lw)[(size_t)vv * D + k]
                         : f2bf(((const float*)lw)[(size_t)vv * D + k]);
            b[j] = (short)bv;
        }
#pragma unroll
        for (int st = 0; st < 8; ++st) {
            short8 aa = *(const short8*)(x1p + (size_t)(st * 16 + col) * DP + k0);
            acc[st] = __builtin_amdgcn_mfma_f32_16x16x32_bf16(aa, b, acc[st], 0, 0, 0);
        }
    }
    if (v < V) {
        float bias = ldf(lb, v, isb);
#pragma unroll
        for (int st = 0; st < 8; ++st) {
#pragma unroll
            for (int i = 0; i < 4; ++i) {
                int s = st * 16 + quad * 4 + i;
                float val = acc[st][i] + bias;
                if (isb)
                    ((ushortT*)out)[(size_t)s * V + v] = f2bf(val);
                else
                    ((float*)out)[(size_t)s * V + v] = val;
            }
        }
    }
}

// ---------------- K8: fused logsumexp + in-place normalize + senses tail ----
__global__ __launch_bounds__(512) void k_norm(const int* __restrict__ flag,
                                              void* __restrict__ out) {
    int isb = flag[0];
    int s = blockIdx.x;
    int t = threadIdx.x;
    __shared__ float red[512];
    if (s == 0 && t < S) {
        if (isb)
            ((ushortT*)out)[(size_t)S * V + t] = 0;
        else
            ((float*)out)[(size_t)S * V + t] = 0.f;
    }
    float mx = -1e30f;
    if (isb) {
        const uint4* row = (const uint4*)((const ushortT*)out + (size_t)s * V);  // 6250 vecs
        for (int i = t; i < 6250; i += 512) {
            uint4 q = row[i];
            mx = fmaxf(mx, fmaxf(fmaxf(bfbits_lo(q.x), bfbits_hi(q.x)),
                                 fmaxf(bfbits_lo(q.y), bfbits_hi(q.y))));
            mx = fmaxf(mx, fmaxf(fmaxf(bfbits_lo(q.z), bfbits_hi(q.z)),
                                 fmaxf(bfbits_lo(q.w), bfbits_hi(q.w))));
        }
    } else {
        const floatx4* row = (const floatx4*)((const float*)out + (size_t)s * V);  // 12500 vecs
        for (int i = t; i < 12500; i += 512) {
            floatx4 q = row[i];
            mx = fmaxf(mx, fmaxf(fmaxf(q[0], q[1]), fmaxf(q[2], q[3])));
        }
    }
    red[t] = mx;
    __syncthreads();
    for (int o = 256; o > 0; o >>= 1) {
        if (t < o) red[t] = fmaxf(red[t], red[t + o]);
        __syncthreads();
    }
    float M = red[0];
    __syncthreads();
    float sm = 0.f;
    if (isb) {
        const uint4* row = (const uint4*)((const ushortT*)out + (size_t)s * V);
        for (int i = t; i < 6250; i += 512) {
            uint4 q = row[i];
            sm += __expf(bfbits_lo(q.x) - M) + __expf(bfbits_hi(q.x) - M) +
                  __expf(bfbits_lo(q.y) - M) + __expf(bfbits_hi(q.y) - M) +
                  __expf(bfbits_lo(q.z) - M) + __expf(bfbits_hi(q.z) - M) +
                  __expf(bfbits_lo(q.w) - M) + __expf(bfbits_hi(q.w) - M);
        }
    } else {
        const floatx4* row = (const floatx4*)((const float*)out + (size_t)s * V);
        for (int i = t; i < 12500; i += 512) {
            floatx4 q = row[i];
            sm += __expf(q[0] - M) + __expf(q[1] - M) + __expf(q[2] - M) + __expf(q[3] - M);
        }
    }
    red[t] = sm;
    __syncthreads();
    for (int o = 256; o > 0; o >>= 1) {
        if (t < o) red[t] += red[t + o];
        __syncthreads();
    }
    float lse = M + __logf(red[0]);
    if (isb) {
        uint4* row = (uint4*)((ushortT*)out + (size_t)s * V);
        for (int i = t; i < 6250; i += 512) {
            uint4 q = row[i];
            uint4 o;
            o.x = (unsigned)f2bf(bfbits_lo(q.x) - lse) |
                  ((unsigned)f2bf(bfbits_hi(q.x) - lse) << 16);
            o.y = (unsigned)f2bf(bfbits_lo(q.y) - lse) |
                  ((unsigned)f2bf(bfbits_hi(q.y) - lse) << 16);
            o.z = (unsigned)f2bf(bfbits_lo(q.z) - lse) |
                  ((unsigned)f2bf(bfbits_hi(q.z) - lse) << 16);
            o.w = (unsigned)f2bf(bfbits_lo(q.w) - lse) |
                  ((unsigned)f2bf(bfbits_hi(q.w) - lse) << 16);
            row[i] = o;
        }
    } else {
        floatx4* row = (floatx4*)((float*)out + (size_t)s * V);
        for (int i = t; i < 12500; i += 512) {
            floatx4 q = row[i];
            q[0] -= lse;
            q[1] -= lse;
            q[2] -= lse;
            q[3] -= lse;
            row[i] = q;
        }
    }
}

// ---------------- workspace layout (bytes, all 256-aligned) -----------------
#define OFF_FLAG 0
#define OFF_GXB 256
#define OFF_WGT 2457856
#define OFF_WST 8294656
#define OFF_YB 9209088
#define OFF_A 9594112
#define OFF_P0 9747712
#define OFF_X1P 9901312
#define OFF_STATS 9983232
#define OFF_PART 9983744  // optional z-split partial buffers (needs bigger ws)
#define PART_A_BYTES (4 * S * D * 4)
#define PART_P_BYTES (2 * S * D * 4)

extern "C" void kernel_launch(void* const* d_in, const int* in_sizes, int n_in, void* d_out,
                              int out_size, void* d_ws, size_t ws_size, hipStream_t stream) {
    const int* xi = (const int*)d_in[0];
    const int* ei = (const int*)d_in[1];
    const int* et = (const int*)d_in[2];
    const void* X = d_in[3];
    const void* convW = d_in[4];
    const void* W0 = d_in[5];
    const void* Wg = d_in[6];
    const void* Ug = d_in[7];
    const void* lw = d_in[8];
    const void* lb = d_in[9];
    char* ws = (char*)d_ws;

    int* flag = (int*)(ws + OFF_FLAG);
    ushortT* gxb = (ushortT*)(ws + OFF_GXB);
    ushortT* wgt = (ushortT*)(ws + OFF_WGT);
    ushortT* wst = (ushortT*)(ws + OFF_WST);
    ushortT* yb = (ushortT*)(ws + OFF_YB);
    float* a = (float*)(ws + OFF_A);
    float* P0 = (float*)(ws + OFF_P0);
    ushortT* x1p = (ushortT*)(ws + OFF_X1P);

    // z-split K only if workspace is big enough for partial buffers
    bool split = ws_size >= (size_t)(OFF_PART + PART_A_BYTES + PART_P_BYTES);
    int nza = split ? 4 : 1;
    int nzp = split ? 2 : 1;
    float* apart = split ? (float*)(ws + OFF_PART) : a;
    float* ppart = split ? (float*)(ws + OFF_PART + PART_A_BYTES) : P0;

    hipLaunchKernelGGL(k_detect, dim3(1), dim3(256), 0, stream, X, flag);
    hipLaunchKernelGGL(k_prep, dim3(ND / 32 + KY / 32, 10), dim3(256), 0, stream, flag, Wg,
                       convW, W0, wgt, wst);
    hipLaunchKernelGGL(k_gyb, dim3(S), dim3(DP), 0, stream, flag, xi, X, ei, et, gxb, yb);
    hipLaunchKernelGGL(k_gemm2, dim3(S / 16, 19, nza + nzp), dim3(256), 0, stream, gxb, wgt,
                       yb, wst, apart, ppart, nza, nzp);
    if (split)
        hipLaunchKernelGGL(k_red2, dim3((S * D + 255) / 256), dim3(256), 0, stream, apart,
                           ppart, a, P0, nza, nzp);
    hipLaunchKernelGGL(k_scan, dim3(1), dim3(768), 0, stream, flag, a, P0, Ug, x1p);
    hipLaunchKernelGGL(k_logits, dim3(VP / 64), dim3(256), 0, stream, flag, x1p, lw, lb, d_out);
    hipLaunchKernelGGL(k_norm, dim3(S), dim3(512), 0, stream, flag, d_out);
}